// Round 4
// baseline (419.328 us; speedup 1.0000x reference)
//
#include <hip/hip_runtime.h>
#include <math.h>

#define NG  16384
#define NN  32
#define DD  128
#define RR  32
#define OO  64
#define HHH 256

// M[o][r] = sum_h Wl[o][h] * V[h][r]   (collapses readout@Wl.T into pooled@M.T)
__global__ void precompute_M_kernel(const float* __restrict__ Wl,
                                    const float* __restrict__ V,
                                    float* __restrict__ M) {
    int t = blockIdx.x * blockDim.x + threadIdx.x;   // 0..2047
    int o = t >> 5;
    int r = t & 31;
    float s = 0.f;
#pragma unroll 8
    for (int hh = 0; hh < HHH; ++hh)
        s = fmaf(Wl[o * HHH + hh], V[hh * RR + r], s);
    M[o * RR + r] = s;
}

typedef const float __attribute__((address_space(1))) gfloat;
typedef float       __attribute__((address_space(3))) lfloat;

// Lane-per-node design: wave = 2 graphs x 32 nodes; lane (gh=l>>5, n=l&31)
// owns acc[r=0..31] for its node. W[d][r] indices are wave-uniform -> s_load
// (SGPR broadcast into v_fma) -> zero LDS traffic for W (R3 spent ~40us of
// LDS pipe re-reading W per graph). h staged global->LDS via global_load_lds
// 16B with XOR-rotated quads: element (row,q) of a 32x32f chunk sits at slot
// (q+row)&7, so reads of quad dq across n hit 8 bank-quads evenly, and DMA
// global addresses stay within one 128B line per row (coalesced).
// Double-buffered chunks, partial s_waitcnt vmcnt(8) (never a full drain
// except the last chunk). No __syncthreads anywhere.
__global__ __launch_bounds__(128, 2)
void gin_main_kernel(const float* __restrict__ hsrc,
                     const float* __restrict__ W,
                     const float* __restrict__ M,
                     const float* __restrict__ bl,
                     float* __restrict__ out) {
    // [wave][slot][2 graphs * 32 rows * 32 floats] = 32 KB/block
    __shared__ float sH[2][2][2048];

    const int tid  = threadIdx.x;
    const int lane = tid & 63;
    const int wv   = tid >> 6;
    const int n    = lane & 31;     // node owned by this lane (compute phase)
    const int gh   = lane >> 5;     // graph half within the pair
    const int rowL = lane >> 3;     // DMA: row within 8-row group
    const int s8   = lane & 7;      // DMA: slot within row
    const int qoff = ((s8 - rowL) & 7) * 4;   // XOR-rotation (float offset)

    const int waveId = blockIdx.x * 2 + wv;   // 0..4095

    // Hoist this lane's two M rows + biases (o = n and n+32) for the epilogue.
    float4 Mr0[8], Mr1[8];
    {
        const float4* M0 = (const float4*)(M + n * RR);
        const float4* M1 = (const float4*)(M + (n + 32) * RR);
#pragma unroll
        for (int i = 0; i < 8; ++i) { Mr0[i] = M0[i]; Mr1[i] = M1[i]; }
    }
    const float bl0 = bl[n], bl1 = bl[n + 32];

    // Stage one 32x32f chunk of each graph of the pair into slot `slot`.
    // 8 DMA instructions total (4 per graph), 1 KB each.
    auto issue_chunk = [&](const float* hg0, const float* hg1, int c, int slot) {
        float* dstb = &sH[wv][slot][0];
        const int goff = c * 32 + qoff;
#pragma unroll
        for (int j = 0; j < 4; ++j) {
            const float* gp = hg0 + (j * 8 + rowL) * DD + goff;
            __builtin_amdgcn_global_load_lds((gfloat*)gp, (lfloat*)(dstb + j * 256), 16, 0, 0);
        }
#pragma unroll
        for (int j = 0; j < 4; ++j) {
            const float* gp = hg1 + (j * 8 + rowL) * DD + goff;
            __builtin_amdgcn_global_load_lds((gfloat*)gp, (lfloat*)(dstb + 1024 + j * 256), 16, 0, 0);
        }
    };

#pragma unroll 1
    for (int pi = 0; pi < 2; ++pi) {
        const int g0 = waveId * 4 + pi * 2;              // pair = graphs g0, g0+1
        const float* hg0 = hsrc + (size_t)g0 * (NN * DD);
        const float* hg1 = hg0 + NN * DD;

        float acc[32];
#pragma unroll
        for (int r = 0; r < 32; ++r) acc[r] = 0.f;

        issue_chunk(hg0, hg1, 0, 0);
        issue_chunk(hg0, hg1, 1, 1);

#pragma unroll
        for (int c = 0; c < 4; ++c) {
            // Wait for chunk c's 8 DMAs; chunk c+1's 8 may remain in flight.
            if (c < 3) asm volatile("s_waitcnt vmcnt(8)" ::: "memory");
            else       asm volatile("s_waitcnt vmcnt(0)" ::: "memory");

            const float* ph = &sH[wv][c & 1][gh * 1024 + n * 32];
            const float* Wc = W + c * 32 * RR;
#pragma unroll 2
            for (int dq = 0; dq < 8; ++dq) {
                float4 hq = *(const float4*)(ph + ((dq + n) & 7) * 4);  // h[n][d..d+3]
                const float4* wr = (const float4*)(Wc + dq * 4 * RR);   // uniform -> s_load
#pragma unroll
                for (int r4 = 0; r4 < 8; ++r4) {
                    float4 w0 = wr[r4];
                    float4 w1 = wr[8 + r4];
                    float4 w2 = wr[16 + r4];
                    float4 w3 = wr[24 + r4];
                    acc[r4*4+0] = fmaf(hq.w, w3.x, fmaf(hq.z, w2.x, fmaf(hq.y, w1.x, fmaf(hq.x, w0.x, acc[r4*4+0]))));
                    acc[r4*4+1] = fmaf(hq.w, w3.y, fmaf(hq.z, w2.y, fmaf(hq.y, w1.y, fmaf(hq.x, w0.y, acc[r4*4+1]))));
                    acc[r4*4+2] = fmaf(hq.w, w3.z, fmaf(hq.z, w2.z, fmaf(hq.y, w1.z, fmaf(hq.x, w0.z, acc[r4*4+2]))));
                    acc[r4*4+3] = fmaf(hq.w, w3.w, fmaf(hq.z, w2.w, fmaf(hq.y, w1.w, fmaf(hq.x, w0.w, acc[r4*4+3]))));
                }
            }
            if (c < 2) issue_chunk(hg0, hg1, c + 2, c & 1);  // refill the slot just consumed
        }

        // pooled[r] = prod over the 32 nodes of this lane's graph half:
        // butterfly over masks 1..16 (stays within the gh half).
#pragma unroll
        for (int m = 1; m <= 16; m <<= 1) {
#pragma unroll
            for (int r = 0; r < 32; ++r)
                acc[r] *= __shfl_xor(acc[r], m);
        }

        // score[g0+gh][o] for o = n and n+32
        float s0 = bl0, s1 = bl1;
#pragma unroll
        for (int i = 0; i < 8; ++i) {
            float4 m0 = Mr0[i], m1 = Mr1[i];
            s0 = fmaf(acc[i*4+0], m0.x, s0);
            s0 = fmaf(acc[i*4+1], m0.y, s0);
            s0 = fmaf(acc[i*4+2], m0.z, s0);
            s0 = fmaf(acc[i*4+3], m0.w, s0);
            s1 = fmaf(acc[i*4+0], m1.x, s1);
            s1 = fmaf(acc[i*4+1], m1.y, s1);
            s1 = fmaf(acc[i*4+2], m1.z, s1);
            s1 = fmaf(acc[i*4+3], m1.w, s1);
        }
        float* og = out + (size_t)(g0 + gh) * OO;
        og[n]      = s0;
        og[n + 32] = s1;
    }
}

extern "C" void kernel_launch(void* const* d_in, const int* in_sizes, int n_in,
                              void* d_out, int out_size, void* d_ws, size_t ws_size,
                              hipStream_t stream) {
    const float* h  = (const float*)d_in[0];   // [16384,32,128]
    const float* W  = (const float*)d_in[1];   // [128,32]
    const float* V  = (const float*)d_in[2];   // [256,32]
    const float* Wl = (const float*)d_in[3];   // [64,256]
    const float* bl = (const float*)d_in[4];   // [64]
    float* out = (float*)d_out;                // [16384,64]
    float* M   = (float*)d_ws;                 // [64,32] scratch

    precompute_M_kernel<<<8, 256, 0, stream>>>(Wl, V, M);
    gin_main_kernel<<<2048, 128, 0, stream>>>(h, W, M, bl, out);
}